// Round 7
// baseline (278.156 us; speedup 1.0000x reference)
//
#include <hip/hip_runtime.h>

// MEASUREMENT PROBE ROUND: the R4 kernel (best, 207.2 us) launched 3x
// back-to-back. The kernel is idempotent, so output is unchanged; the
// bench delta vs R4 gives the true per-launch slice duration:
//   slice_warm = (dur_us - 207.2) / 2
// This pins the controllable budget that three falsified write-path
// theories (XCD swizzle +6.4, nt stores +10.2) were guessing at.
//
// Kernel body is bit-identical to R4:
// - one block per row pair (shared by), 512 threads, 4 px/thread
// - LDS r[row][x][z][c], XSTR=100: taps = 4x ds_read_b128, imm offsets
// - plain float4 stores (nt regressed; L3 absorbs and drains lazily)

#define NN 4
#define CC 12
#define GD_ 8
#define GH_ 16
#define GW_ 16
#define HH 1024
#define WW 1024

#define ZSTR 12    // z stride in dwords (= CC)
#define XSTR 100   // x stride in dwords

__global__ __launch_bounds__(512) void slice_kernel(
    const float* __restrict__ grid,   // (N, C, GD, GH, GW)
    const float* __restrict__ guide,  // (N, 1, H, W)
    float* __restrict__ out)          // (N, C, H, W)
{
    __shared__ float r[2][GW_ * XSTR];   // 2 x 1600 dwords = 12.8 KB

    const int bid  = blockIdx.x;         // 0 .. N*H/2-1
    const int n    = bid >> 9;
    const int y0   = (bid & 511) << 1;   // even row
    const int tid  = threadIdx.x;        // 0..511
    const int rsel = tid >> 8;           // 0: row y0, 1: row y0+1 (wave-uniform)
    const int lane = tid & 255;
    const int y    = y0 + rsel;

    // ---- guide load first: HBM latency hides under staging ----
    const float4 g4 = ((const float4*)guide)[((size_t)n * HH + y) * (WW / 4) + lane];

    // ---- y weights for both rows (shared by) ----
    float ys0 = ((float)y0 + 0.5f) * (1.0f / 64.0f);   // * GH / H
    float fy  = floorf(ys0 - 0.5f);
    int   by  = (int)fy;
    by = by < 0 ? 0 : (by > GH_ - 2 ? GH_ - 2 : by);
    float ty0 = (ys0 - 0.5f) - (float)by;
    ty0 = ty0 < 0.0f ? 0.0f : (ty0 > 1.0f ? 1.0f : ty0);
    float ty1 = (ys0 + (1.0f / 64.0f) - 0.5f) - (float)by;
    ty1 = ty1 < 0.0f ? 0.0f : (ty1 > 1.0f ? 1.0f : ty1);

    // ---- stage y-lerped grid for BOTH rows, fully unrolled ----
    const float* gbase = grid + (size_t)n * (CC * GD_ * GH_ * GW_) + by * GW_;
#pragma unroll
    for (int it = 0; it < 3; ++it) {
        int idx = tid + it * 512;      // 0..1535
        int gx = idx & 15;
        int z  = (idx >> 4) & 7;
        int c  = idx >> 7;
        const float* gp = gbase + ((c * GD_ + z) * GH_) * GW_ + gx;
        float g0 = gp[0];
        float g1 = gp[GW_];
        int a = gx * XSTR + z * ZSTR + c;
        r[0][a] = (1.0f - ty0) * g0 + ty0 * g1;
        r[1][a] = (1.0f - ty1) * g0 + ty1 * g1;
    }

    // ---- per-pixel setup BEFORE the barrier (no LDS dependency) ----
    const int x0 = lane * 4;
    float xs  = ((float)x0 + 0.5f) * (1.0f / 64.0f);  // * GW / W
    float fx  = floorf(xs - 0.5f);
    int   bx  = (int)fx;
    bx = bx < 0 ? 0 : (bx > GW_ - 2 ? GW_ - 2 : bx);
    const float txb = (xs - 0.5f) - (float)bx;

    float gz[4] = {g4.x, g4.y, g4.z, g4.w};
    int   aoff[4];
    float w00[4], w01[4], w10[4], w11[4];
#pragma unroll
    for (int j = 0; j < 4; ++j) {
        float tx = txb + (float)j * (1.0f / 64.0f);
        tx = tx < 0.0f ? 0.0f : (tx > 1.0f ? 1.0f : tx);

        float zs = gz[j] * 8.0f;                      // * GD
        float fz = floorf(zs - 0.5f);
        int   bz = (int)fz;
        bz = bz < 0 ? 0 : (bz > GD_ - 2 ? GD_ - 2 : bz);
        float tz = (zs - 0.5f) - (float)bz;
        tz = tz < 0.0f ? 0.0f : (tz > 1.0f ? 1.0f : tz);

        aoff[j] = bx * XSTR + bz * ZSTR;
        float tx0 = 1.0f - tx, tz0 = 1.0f - tz;
        w00[j] = tz0 * tx0;  w01[j] = tz0 * tx;       // (bx,bz)   (bx+1,bz)
        w10[j] = tz  * tx0;  w11[j] = tz  * tx;       // (bx,bz+1) (bx+1,bz+1)
    }

    __syncthreads();

    // ---- channel loop: taps = 4x ds_read_b128, imm offsets; f4 stores ----
    const float* rr = r[rsel];
    float4* out4 = (float4*)out + ((size_t)(n * CC) * HH + y) * (WW / 4) + lane;
#pragma unroll
    for (int g = 0; g < 3; ++g) {
        float acc[4][4];                 // [cc][j]
#pragma unroll
        for (int j = 0; j < 4; ++j) {
            const float* p = rr + aoff[j] + 4 * g;
            const float4 t00 = *(const float4*)(p);                 // (bx,  bz)
            const float4 t10 = *(const float4*)(p + ZSTR);          // (bx,  bz+1)
            const float4 t01 = *(const float4*)(p + XSTR);          // (bx+1,bz)
            const float4 t11 = *(const float4*)(p + XSTR + ZSTR);   // (bx+1,bz+1)
            acc[0][j] = w00[j]*t00.x + w10[j]*t10.x + w01[j]*t01.x + w11[j]*t11.x;
            acc[1][j] = w00[j]*t00.y + w10[j]*t10.y + w01[j]*t01.y + w11[j]*t11.y;
            acc[2][j] = w00[j]*t00.z + w10[j]*t10.z + w01[j]*t01.z + w11[j]*t11.z;
            acc[3][j] = w00[j]*t00.w + w10[j]*t10.w + w01[j]*t01.w + w11[j]*t11.w;
        }
#pragma unroll
        for (int cc = 0; cc < 4; ++cc) {
            int c = 4 * g + cc;
            out4[(size_t)c * (HH * WW / 4)] =
                make_float4(acc[cc][0], acc[cc][1], acc[cc][2], acc[cc][3]);
        }
    }
}

extern "C" void kernel_launch(void* const* d_in, const int* in_sizes, int n_in,
                              void* d_out, int out_size, void* d_ws, size_t ws_size,
                              hipStream_t stream) {
    const float* grid  = (const float*)d_in[0];
    const float* guide = (const float*)d_in[1];
    float* out = (float*)d_out;
    dim3 gridDim(NN * HH / 2);
    dim3 blockDim(512);
    // PROBE: 3 identical launches (idempotent). slice_warm = (dur - 207.2)/2.
    hipLaunchKernelGGL(slice_kernel, gridDim, blockDim, 0, stream, grid, guide, out);
    hipLaunchKernelGGL(slice_kernel, gridDim, blockDim, 0, stream, grid, guide, out);
    hipLaunchKernelGGL(slice_kernel, gridDim, blockDim, 0, stream, grid, guide, out);
}

// Round 8
// 208.398 us; speedup vs baseline: 1.3347x; 1.3347x over previous
//
#include <hip/hip_runtime.h>

// Bilateral slice: grid (N=4, C=12, GD=8, GH=16, GW=16) fp32,
// guide (N,1,1024,1024) fp32 -> out (N, C, 1024, 1024) fp32.
//
// FINAL (R4 structure, 207.2 us measured; slice kernel itself ~35.5 us warm
// per the R7 3x-launch probe = 92-95% of the achievable memory roofline:
// 219 MB mandatory traffic at the fill-demonstrated 6.6-6.8 TB/s = 32-33 us).
//
// One block per ROW PAIR (y, y+1); row pairs always share the y-cell `by`
// (fy increments between y=64k+31 and 64k+32, an even-aligned boundary),
// so one set of grid loads feeds both rows' y-lerped LDS tables.
//
// Measured dead ends (do not re-apply):
//  - XCD-aware block swizzle: +6.4 us (output is L3-absorbed; concentrating
//    per-XCD write windows worsens L2 churn).
//  - __builtin_nontemporal_store: +10.2 us (L3 write absorption + lazy drain
//    beats allocation bypass here).
//  - r[x][z][c]-with-ds_read2 variant (R1): +12.5 us vs paired-offset layout.
//
// LDS layout r[row][x][z][c], dword index = x*100 + z*12 + c:
//  - channels contiguous -> the 4 taps for a 4-channel group are 4x
//    ds_read_b128 at immediate byte offsets {0,48,400,448}+16*g from ONE
//    per-pixel base: 12 LDS instr/pixel (the 16B/lane floor), zero address
//    VALU in the channel loop.
//  - XSTR=100 = 4 (mod 32), multiple of 4: 16B-aligned float4 reads,
//    bank collisions <=2-way (free) on staging writes and tap reads.

#define NN 4
#define CC 12
#define GD_ 8
#define GH_ 16
#define GW_ 16
#define HH 1024
#define WW 1024

#define ZSTR 12    // z stride in dwords (= CC)
#define XSTR 100   // x stride in dwords

__global__ __launch_bounds__(512) void slice_kernel(
    const float* __restrict__ grid,   // (N, C, GD, GH, GW)
    const float* __restrict__ guide,  // (N, 1, H, W)
    float* __restrict__ out)          // (N, C, H, W)
{
    __shared__ float r[2][GW_ * XSTR];   // 2 x 1600 dwords = 12.8 KB

    const int bid  = blockIdx.x;         // 0 .. N*H/2-1
    const int n    = bid >> 9;
    const int y0   = (bid & 511) << 1;   // even row
    const int tid  = threadIdx.x;        // 0..511
    const int rsel = tid >> 8;           // 0: row y0, 1: row y0+1 (wave-uniform)
    const int lane = tid & 255;
    const int y    = y0 + rsel;

    // ---- guide load first: HBM latency hides under staging ----
    const float4 g4 = ((const float4*)guide)[((size_t)n * HH + y) * (WW / 4) + lane];

    // ---- y weights for both rows (shared by) ----
    float ys0 = ((float)y0 + 0.5f) * (1.0f / 64.0f);   // * GH / H
    float fy  = floorf(ys0 - 0.5f);
    int   by  = (int)fy;
    by = by < 0 ? 0 : (by > GH_ - 2 ? GH_ - 2 : by);
    float ty0 = (ys0 - 0.5f) - (float)by;
    ty0 = ty0 < 0.0f ? 0.0f : (ty0 > 1.0f ? 1.0f : ty0);
    float ty1 = (ys0 + (1.0f / 64.0f) - 0.5f) - (float)by;
    ty1 = ty1 < 0.0f ? 0.0f : (ty1 > 1.0f ? 1.0f : ty1);

    // ---- stage y-lerped grid for BOTH rows, fully unrolled ----
    const float* gbase = grid + (size_t)n * (CC * GD_ * GH_ * GW_) + by * GW_;
#pragma unroll
    for (int it = 0; it < 3; ++it) {
        int idx = tid + it * 512;      // 0..1535
        int gx = idx & 15;
        int z  = (idx >> 4) & 7;
        int c  = idx >> 7;
        const float* gp = gbase + ((c * GD_ + z) * GH_) * GW_ + gx;
        float g0 = gp[0];
        float g1 = gp[GW_];
        int a = gx * XSTR + z * ZSTR + c;
        r[0][a] = (1.0f - ty0) * g0 + ty0 * g1;
        r[1][a] = (1.0f - ty1) * g0 + ty1 * g1;
    }

    // ---- per-pixel setup BEFORE the barrier (no LDS dependency) ----
    // bx uniform across a thread's 4 aligned pixels (fx changes at x=64k+32).
    const int x0 = lane * 4;
    float xs  = ((float)x0 + 0.5f) * (1.0f / 64.0f);  // * GW / W
    float fx  = floorf(xs - 0.5f);
    int   bx  = (int)fx;
    bx = bx < 0 ? 0 : (bx > GW_ - 2 ? GW_ - 2 : bx);
    const float txb = (xs - 0.5f) - (float)bx;

    float gz[4] = {g4.x, g4.y, g4.z, g4.w};
    int   aoff[4];
    float w00[4], w01[4], w10[4], w11[4];
#pragma unroll
    for (int j = 0; j < 4; ++j) {
        float tx = txb + (float)j * (1.0f / 64.0f);
        tx = tx < 0.0f ? 0.0f : (tx > 1.0f ? 1.0f : tx);

        float zs = gz[j] * 8.0f;                      // * GD
        float fz = floorf(zs - 0.5f);
        int   bz = (int)fz;
        bz = bz < 0 ? 0 : (bz > GD_ - 2 ? GD_ - 2 : bz);
        float tz = (zs - 0.5f) - (float)bz;
        tz = tz < 0.0f ? 0.0f : (tz > 1.0f ? 1.0f : tz);

        aoff[j] = bx * XSTR + bz * ZSTR;
        float tx0 = 1.0f - tx, tz0 = 1.0f - tz;
        w00[j] = tz0 * tx0;  w01[j] = tz0 * tx;       // (bx,bz)   (bx+1,bz)
        w10[j] = tz  * tx0;  w11[j] = tz  * tx;       // (bx,bz+1) (bx+1,bz+1)
    }

    __syncthreads();

    // ---- channel loop: 3 groups of 4 channels; per (group, pixel) the 4
    //      taps are 4x ds_read_b128, immediate offsets only ----
    const float* rr = r[rsel];
    float4* out4 = (float4*)out + ((size_t)(n * CC) * HH + y) * (WW / 4) + lane;
#pragma unroll
    for (int g = 0; g < 3; ++g) {
        float acc[4][4];                 // [cc][j]
#pragma unroll
        for (int j = 0; j < 4; ++j) {
            const float* p = rr + aoff[j] + 4 * g;
            const float4 t00 = *(const float4*)(p);                 // (bx,  bz)
            const float4 t10 = *(const float4*)(p + ZSTR);          // (bx,  bz+1)
            const float4 t01 = *(const float4*)(p + XSTR);          // (bx+1,bz)
            const float4 t11 = *(const float4*)(p + XSTR + ZSTR);   // (bx+1,bz+1)
            acc[0][j] = w00[j]*t00.x + w10[j]*t10.x + w01[j]*t01.x + w11[j]*t11.x;
            acc[1][j] = w00[j]*t00.y + w10[j]*t10.y + w01[j]*t01.y + w11[j]*t11.y;
            acc[2][j] = w00[j]*t00.z + w10[j]*t10.z + w01[j]*t01.z + w11[j]*t11.z;
            acc[3][j] = w00[j]*t00.w + w10[j]*t10.w + w01[j]*t01.w + w11[j]*t11.w;
        }
#pragma unroll
        for (int cc = 0; cc < 4; ++cc) {
            int c = 4 * g + cc;
            out4[(size_t)c * (HH * WW / 4)] =
                make_float4(acc[cc][0], acc[cc][1], acc[cc][2], acc[cc][3]);
        }
    }
}

extern "C" void kernel_launch(void* const* d_in, const int* in_sizes, int n_in,
                              void* d_out, int out_size, void* d_ws, size_t ws_size,
                              hipStream_t stream) {
    const float* grid  = (const float*)d_in[0];
    const float* guide = (const float*)d_in[1];
    float* out = (float*)d_out;
    dim3 gridDim(NN * HH / 2);
    dim3 blockDim(512);
    hipLaunchKernelGGL(slice_kernel, gridDim, blockDim, 0, stream, grid, guide, out);
}